// Round 4
// baseline (591.788 us; speedup 1.0000x reference)
//
#include <hip/hip_runtime.h>

// Problem constants
#define HALF   20000
#define MSEL   6001        // top-30%: 20000 - int(0.7*20000)=13999 -> 6001
#define RANKLO 13999       // = HALF - MSEL
#define NBUCK  4096
#define CANDMAX 8192

// k_solve geometry
#define NTH   1024
#define TPT   6            // 6*1024 = 6144 >= 6016
#define NPAD  6016
#define NCH   188          // NPAD/32 chunks of 32

// Workspace offsets (4-byte elements), no overlays
#define OFF_HIST   0        // int[2][4096]
#define OFF_TSEL   8192     // int[2]
#define OFF_CCNT   8194     // int[2]
#define OFF_ZERO_N 8196
#define OFF_CANDV  8704     // float[2][8192]
#define OFF_CANDI  25088    // int[2][8192]
#define OFF_RANK   41472    // int[2][8192]
#define OFF_XS     57856    // float[6016] sorted top of half0
#define OFF_YS     63872    // float[6016] sorted top of half1

// k_solve LDS layout (floats)
#define LY0 0
#define LX0 6016
#define LCX 12032
#define LCY 18048
#define LA  24064
#define LB  30080
#define LPA 36096   // 192
#define LPB 36288   // 192
#define LRED 36480  // 64
#define LSC 36544   // 16
#define SOLVE_LDS_FLOATS 36560
#define SOLVE_LDS_BYTES (SOLVE_LDS_FLOATS * 4)

__device__ __forceinline__ float fexp2(float x) {
#if defined(__has_builtin)
#if __has_builtin(__builtin_amdgcn_exp2f)
  return __builtin_amdgcn_exp2f(x);
#else
  return exp2f(x);
#endif
#else
  return exp2f(x);
#endif
}

__device__ __forceinline__ int bucket_of(float v) {
  int b = (int)(v * 4096.0f);
  b = b < 0 ? 0 : b;
  b = b > (NBUCK - 1) ? (NBUCK - 1) : b;
  return b;
}

// ---------------- selection kernels (verified in R2/R3) ----------------

__global__ __launch_bounds__(512) void k_zero(int* wsI) {
  int i = blockIdx.x * blockDim.x + threadIdx.x;
  if (i < OFF_ZERO_N) wsI[i] = 0;
  if (i < 2 * CANDMAX) wsI[OFF_RANK + i] = 0;
}

__global__ __launch_bounds__(512) void k_hist(const float* __restrict__ yp, int* wsI) {
  int i = blockIdx.x * blockDim.x + threadIdx.x;
  if (i >= 2 * HALF) return;
  int h = (i >= HALF) ? 1 : 0;
  atomicAdd(&wsI[OFF_HIST + h * NBUCK + bucket_of(yp[i])], 1);
}

__global__ __launch_bounds__(1024) void k_findt(int* wsI) {
  __shared__ int ss[1024];
  const int h = blockIdx.x;
  const int t = threadIdx.x;
  const int* hist = wsI + OFF_HIST + h * NBUCK;
  int c0 = hist[4 * t + 0], c1 = hist[4 * t + 1], c2 = hist[4 * t + 2], c3 = hist[4 * t + 3];
  ss[t] = c0 + c1 + c2 + c3;
  __syncthreads();
  for (int off = 1; off < 1024; off <<= 1) {
    int v = ss[t];
    if (t + off < 1024) v += ss[t + off];
    __syncthreads();
    ss[t] = v;
    __syncthreads();
  }
  int SSnext = (t < 1023) ? ss[t + 1] : 0;
  int R3 = c3 + SSnext;
  int R2 = c2 + R3;
  int R1 = c1 + R2;
  int R0 = c0 + R1;
  if (R0 >= MSEL && R1 < MSEL) wsI[OFF_TSEL + h] = 4 * t + 0;
  if (R1 >= MSEL && R2 < MSEL) wsI[OFF_TSEL + h] = 4 * t + 1;
  if (R2 >= MSEL && R3 < MSEL) wsI[OFF_TSEL + h] = 4 * t + 2;
  if (R3 >= MSEL && SSnext < MSEL) wsI[OFF_TSEL + h] = 4 * t + 3;
}

__global__ __launch_bounds__(512) void k_cand(const float* __restrict__ yp, int* wsI, float* wsF) {
  __shared__ int ss[512];
  __shared__ int sbase;
  const int h = blockIdx.y;
  const int tid = threadIdx.x;
  const int idx = blockIdx.x * 512 + tid;
  float v = 0.f;
  int flag = 0;
  if (idx < HALF) {
    v = yp[h * HALF + idx];
    flag = (bucket_of(v) >= wsI[OFF_TSEL + h]) ? 1 : 0;
  }
  ss[tid] = flag;
  __syncthreads();
  for (int off = 1; off < 512; off <<= 1) {
    int add = (tid >= off) ? ss[tid - off] : 0;
    __syncthreads();
    ss[tid] += add;
    __syncthreads();
  }
  if (tid == 511) sbase = atomicAdd(&wsI[OFF_CCNT + h], ss[511]);
  __syncthreads();
  if (flag) {
    int pos = sbase + ss[tid] - 1;
    if (pos < CANDMAX) {
      wsF[OFF_CANDV + h * CANDMAX + pos] = v;
      wsI[OFF_CANDI + h * CANDMAX + pos] = idx;
    }
  }
}

__global__ __launch_bounds__(512) void k_rankc(const int* __restrict__ wsIc, float* wsF, int* wsI) {
  __shared__ float cv[512];
  __shared__ int ci[512];
  const int h = blockIdx.z;
  const int tid = threadIdx.x;
  const int cnt = min(wsIc[OFF_CCNT + h], CANDMAX);
  const int cb = blockIdx.y * 512;
  if (cb >= cnt) return;
  const int clen = min(512, cnt - cb);
  if (tid < clen) {
    cv[tid] = wsF[OFF_CANDV + h * CANDMAX + cb + tid];
    ci[tid] = wsIc[OFF_CANDI + h * CANDMAX + cb + tid];
  }
  __syncthreads();
  const int g = blockIdx.x * 512 + tid;
  if (g >= cnt) return;
  const float v = wsF[OFF_CANDV + h * CANDMAX + g];
  const int li = wsIc[OFF_CANDI + h * CANDMAX + g];
  int r = 0;
  for (int l = 0; l < clen; ++l) {
    float w = cv[l];
    r += (w < v || (w == v && ci[l] < li)) ? 1 : 0;
  }
  atomicAdd(&wsI[OFF_RANK + h * CANDMAX + g], r);
}

__global__ __launch_bounds__(512) void k_place(const int* __restrict__ wsI, float* wsF) {
  const int h = blockIdx.y;
  const int g = blockIdx.x * 512 + threadIdx.x;
  const int cnt = min(wsI[OFF_CCNT + h], CANDMAX);
  if (g >= cnt) return;
  const int full = wsI[OFF_RANK + h * CANDMAX + g] + (HALF - cnt);
  if (full >= RANKLO) {
    wsF[(h ? OFF_YS : OFF_XS) + (full - RANKLO)] = wsF[OFF_CANDV + h * CANDMAX + g];
  }
}

// ---------------- persistent Sinkhorn solver (single block) ----------------

__device__ __forceinline__ float block_reduce(float v, float* red) {
  const int tid = threadIdx.x;
  __syncthreads();
  for (int d = 1; d < 64; d <<= 1) v += __shfl_xor(v, d, 64);
  if ((tid & 63) == 0) red[tid >> 6] = v;
  __syncthreads();
  float r = 0.f;
  if (tid < 16) {
    r = red[tid];
    for (int d = 1; d < 16; d <<= 1) r += __shfl_xor(r, d, 16);
    if (tid == 0) red[0] = r;
  }
  __syncthreads();
  return red[0];
}

// per-chunk (32 elems) totals of A and B -> PA/PB raw
__device__ __forceinline__ void chunk_sums(const float* A, const float* B, float* PA, float* PB) {
  const int tid = threadIdx.x;
  const int wave = tid >> 6, lane = tid & 63;
  for (int task = wave; task < NPAD / 64; task += NTH / 64) {  // 94 tasks, 2 chunks each
    float a = A[task * 64 + lane];
    float b = B[task * 64 + lane];
    for (int d = 1; d < 32; d <<= 1) {
      a += __shfl_xor(a, d, 64);
      b += __shfl_xor(b, d, 64);
    }
    if ((lane & 31) == 0) {
      int c = task * 2 + (lane >> 5);
      PA[c] = a;
      PB[c] = b;
    }
  }
}

// PA <- exclusive left prefix over chunks (PA[NCH] = total);
// PB <- inclusive right suffix over chunks (PB[NCH] = 0).
__device__ __forceinline__ void chunk_scan(float* PA, float* PB) {
  const int tid = threadIdx.x;
  if (tid < 64) {
    const int c0 = 3 * tid;
    float a0 = (c0 < NCH) ? PA[c0] : 0.f;
    float a1 = (c0 + 1 < NCH) ? PA[c0 + 1] : 0.f;
    float a2 = (c0 + 2 < NCH) ? PA[c0 + 2] : 0.f;
    float b0 = (c0 < NCH) ? PB[c0] : 0.f;
    float b1 = (c0 + 1 < NCH) ? PB[c0 + 1] : 0.f;
    float b2 = (c0 + 2 < NCH) ? PB[c0 + 2] : 0.f;
    float ta = a0 + a1 + a2;
    float tb = b0 + b1 + b2;
    float sa = ta;
    for (int d = 1; d < 64; d <<= 1) {
      float o = __shfl_up(sa, d, 64);
      if (tid >= d) sa += o;
    }
    float sb = tb;
    for (int d = 1; d < 64; d <<= 1) {
      float o = __shfl_down(sb, d, 64);
      if (tid + d < 64) sb += o;
    }
    float ea = sa - ta;   // sum of lanes < tid (left)
    float nb = sb - tb;   // sum of lanes > tid (right)
    PA[c0] = ea;
    PA[c0 + 1] = ea + a0;
    PA[c0 + 2] = ea + a0 + a1;
    PB[c0 + 2] = b2 + nb;
    PB[c0 + 1] = b1 + (b2 + nb);
    PB[c0] = b0 + (b1 + (b2 + nb));
  }
}

__device__ __forceinline__ float eval_left(const float* A, const float* PA, int p) {
  int cb = p >> 5;
  float s = PA[cb];
  for (int j = cb * 32; j < p; ++j) s += A[j];
  return s;
}

__device__ __forceinline__ float eval_right(const float* B, const float* PB, int p) {
  int cb = p >> 5;
  float s = PB[cb + 1];
  int e = cb * 32 + 32;
  for (int j = p; j < e; ++j) s += B[j];
  return s;
}

__device__ __forceinline__ int bsearch(const float* arr, float v) {
  int lo = 0, hi = MSEL;
  while (lo < hi) {
    int m = (lo + hi) >> 1;
    if (arr[m] <= v) lo = m + 1; else hi = m;
  }
  return lo;
}

// One Sinkhorn matvec pass via sorted prefix/suffix sums.
// mode 0: uniform weights au (pass0, no state)
// mode 1: state in = first-pass constants (S=MSEL*au, l=0.5)
// mode 2: state in = scal[sin], scal[lin]
__device__ void do_pass(float* lds, const float* srcv, const float* zin, float* zout,
                        const float (&tv)[TPT], const int (&tp)[TPT],
                        int mode, int sin, int lin, int sout, int lout) {
  float* A = lds + LA;
  float* B = lds + LB;
  float* PA = lds + LPA;
  float* PB = lds + LPB;
  float* red = lds + LRED;
  float* scal = lds + LSC;
  const int tid = threadIdx.x;
  const float au = 0.5f / 20000.0f;
  const float lamL2 = scal[0], kd = scal[2], mid = scal[3];
  float S_in = 0.f, l_in = 0.f, cin = 0.f;
  if (mode == 1) { S_in = (float)MSEL * au; l_in = 0.5f; }
  else if (mode == 2) { S_in = scal[sin]; l_in = scal[lin]; }
  if (mode) cin = 1e-6f * S_in + l_in * kd;

  float wsum = 0.f;
#pragma unroll
  for (int k = 0; k < TPT; ++k) {
    int j = tid + k * NTH;
    if (j < NPAD) {
      float a = 0.f, b = 0.f;
      if (j < MSEL) {
        float w = mode ? (au / (zin[j] + cin)) : au;
        wsum += w;
        float Y = lamL2 * (srcv[j] - mid);
        a = w * fexp2(Y);
        b = w * fexp2(-Y);
      }
      A[j] = a;
      B[j] = b;
    }
  }
  if (mode) {
    float S = block_reduce(wsum, red);
    if (tid == 0) {
      scal[sout] = S;
      scal[lout] = 0.5f / (kd * S_in + l_in * (1.0f + 1e-6f));
    }
  }
  __syncthreads();
  chunk_sums(A, B, PA, PB);
  __syncthreads();
  chunk_scan(PA, PB);
  __syncthreads();
#pragma unroll
  for (int k = 0; k < TPT; ++k) {
    int i = tid + k * NTH;
    if (i < MSEL) {
      float X = lamL2 * (tv[k] - mid);
      float L = eval_left(A, PA, tp[k]);
      float R = eval_right(B, PB, tp[k]);
      zout[i] = fexp2(-X) * L + fexp2(X) * R;
    }
  }
  __syncthreads();
}

__global__ __launch_bounds__(NTH) void k_solve(float* __restrict__ wsF, float* __restrict__ out) {
  extern __shared__ float lds[];
  const int tid = threadIdx.x;
  float* ys = lds + LY0;
  float* xs = lds + LX0;
  float* cx = lds + LCX;
  float* cy = lds + LCY;
  float* A = lds + LA;
  float* B = lds + LB;
  float* PA = lds + LPA;
  float* PB = lds + LPB;
  float* red = lds + LRED;
  float* scal = lds + LSC;
  const float au = 0.5f / 20000.0f;

  // load sorted arrays (pad with +inf for search safety)
#pragma unroll
  for (int k = 0; k < TPT; ++k) {
    int j = tid + k * NTH;
    if (j < NPAD) {
      xs[j] = (j < MSEL) ? wsF[OFF_XS + j] : 1e30f;
      ys[j] = (j < MSEL) ? wsF[OFF_YS + j] : 1e30f;
    }
  }
  __syncthreads();

  // per-thread target caches + merge positions (lambda-independent)
  float xv[TPT], yv[TPT];
  int px[TPT], py[TPT];
#pragma unroll
  for (int k = 0; k < TPT; ++k) {
    int i = tid + k * NTH;
    if (i < MSEL) {
      xv[k] = xs[i];
      yv[k] = ys[i];
      px[k] = bsearch(ys, xv[k]);   // #{ys <= x}
      py[k] = bsearch(xs, yv[k]);   // #{xs <= y}
    } else { xv[k] = 0.f; yv[k] = 0.f; px[k] = 0; py[k] = 0; }
  }

  // meanM via prefix sums of ys: sum_j |x - y_j| = x(2p-m) + PyT - 2 Py(p)
#pragma unroll
  for (int k = 0; k < TPT; ++k) {
    int j = tid + k * NTH;
    if (j < NPAD) {
      A[j] = (j < MSEL) ? ys[j] : 0.f;
      B[j] = 0.f;
    }
  }
  __syncthreads();
  chunk_sums(A, B, PA, PB);
  __syncthreads();
  chunk_scan(PA, PB);
  __syncthreads();
  float rs = 0.f;
  const float PyT = PA[NCH];
#pragma unroll
  for (int k = 0; k < TPT; ++k) {
    int i = tid + k * NTH;
    if (i < MSEL) {
      float Py = eval_left(A, PA, px[k]);
      rs += xv[k] * (float)(2 * px[k] - MSEL) + PyT - 2.f * Py;
    }
  }
  float tot = block_reduce(rs, red);
  if (tid == 0) {
    float meanM = tot / ((float)MSEL * (float)MSEL);
    float lam = 10.0f / meanM;
    float lamL2 = lam * 1.4426950408889634f;
    float delta = fmaxf(ys[MSEL - 1] - xs[0], xs[MSEL - 1] - ys[0]);
    float kd = fexp2(-lamL2 * delta) + 1e-6f;
    float lo = fminf(xs[0], ys[0]);
    float hi = fmaxf(xs[MSEL - 1], ys[MSEL - 1]);
    scal[0] = lamL2;
    scal[1] = delta;
    scal[2] = kd;
    scal[3] = 0.5f * (lo + hi);
  }
  __syncthreads();

  // Sinkhorn chain: pass0 (uniform u0) then 10x (X->Y, Y->X).
  // scal slots: 4=Sx, 5=Sy, 6=lX, 7=lY
  do_pass(lds, ys, cx, cx, xv, px, 0, 0, 0, 0, 0);
  for (int it = 0; it < 10; ++it) {
    do_pass(lds, xs, cx, cy, yv, py, (it == 0) ? 1 : 2, 5, 7, 4, 6);
    do_pass(lds, ys, cy, cx, xv, px, 2, 4, 6, 5, 7);
  }

  // D-pass
  const float lamL2 = scal[0], delta = scal[1], kd = scal[2], mid = scal[3];
  const float Sx = scal[4], Sy = scal[5], lX = scal[6], lY = scal[7];
  const float cin_v = 1e-6f * Sy + lY * kd;
  const float cin_u = 1e-6f * Sx + lX * kd;

  // v = au/(cx + cin_v) stored into cx; Sv, TVX reductions
  float sv = 0.f, svx = 0.f;
#pragma unroll
  for (int k = 0; k < TPT; ++k) {
    int j = tid + k * NTH;
    if (j < MSEL) {
      float v = au / (cx[j] + cin_v);
      cx[j] = v;
      sv += v;
      svx += v * xs[j];
    }
  }
  const float Sv = block_reduce(sv, red);
  const float TVX = block_reduce(svx, red);

  float dv[TPT];
#pragma unroll
  for (int k = 0; k < TPT; ++k) dv[k] = 0.f;

  // sub-phase 1: A=v*2^X, B=v*2^-X  ->  y*(T1 - T3)
#pragma unroll
  for (int k = 0; k < TPT; ++k) {
    int j = tid + k * NTH;
    if (j < NPAD) {
      float a = 0.f, b = 0.f;
      if (j < MSEL) {
        float v = cx[j];
        float X = lamL2 * (xs[j] - mid);
        a = v * fexp2(X);
        b = v * fexp2(-X);
      }
      A[j] = a; B[j] = b;
    }
  }
  __syncthreads();
  chunk_sums(A, B, PA, PB);
  __syncthreads();
  chunk_scan(PA, PB);
  __syncthreads();
#pragma unroll
  for (int k = 0; k < TPT; ++k) {
    int i = tid + k * NTH;
    if (i < MSEL) {
      float Y = lamL2 * (yv[k] - mid);
      float P1 = eval_left(A, PA, py[k]);
      float S1 = eval_right(B, PB, py[k]);
      dv[k] += yv[k] * (fexp2(-Y) * P1 - fexp2(Y) * S1);
    }
  }
  __syncthreads();

  // sub-phase 2: A=v*x*2^X, B=v*x*2^-X  ->  -T2 + T4
#pragma unroll
  for (int k = 0; k < TPT; ++k) {
    int j = tid + k * NTH;
    if (j < NPAD) {
      float a = 0.f, b = 0.f;
      if (j < MSEL) {
        float vx = cx[j] * xs[j];
        float X = lamL2 * (xs[j] - mid);
        a = vx * fexp2(X);
        b = vx * fexp2(-X);
      }
      A[j] = a; B[j] = b;
    }
  }
  __syncthreads();
  chunk_sums(A, B, PA, PB);
  __syncthreads();
  chunk_scan(PA, PB);
  __syncthreads();
#pragma unroll
  for (int k = 0; k < TPT; ++k) {
    int i = tid + k * NTH;
    if (i < MSEL) {
      float Y = lamL2 * (yv[k] - mid);
      float P2 = eval_left(A, PA, py[k]);
      float S2 = eval_right(B, PB, py[k]);
      dv[k] += -fexp2(-Y) * P2 + fexp2(Y) * S2;
    }
  }
  __syncthreads();

  // sub-phase 3: A=v, B=v*x  ->  1e-6 * ( y*(2*P5 - Sv) + 2*S6 - TVX )
#pragma unroll
  for (int k = 0; k < TPT; ++k) {
    int j = tid + k * NTH;
    if (j < NPAD) {
      float a = 0.f, b = 0.f;
      if (j < MSEL) {
        a = cx[j];
        b = cx[j] * xs[j];
      }
      A[j] = a; B[j] = b;
    }
  }
  __syncthreads();
  chunk_sums(A, B, PA, PB);
  __syncthreads();
  chunk_scan(PA, PB);
  __syncthreads();
  float acc = 0.f;
#pragma unroll
  for (int k = 0; k < TPT; ++k) {
    int i = tid + k * NTH;
    if (i < MSEL) {
      float P5 = eval_left(A, PA, py[k]);
      float S6 = eval_right(B, PB, py[k]);
      float d6 = dv[k] + 1e-6f * (yv[k] * (2.f * P5 - Sv) + 2.f * S6 - TVX);
      float u = au / (cy[i] + cin_u);
      acc += u * d6;
    }
  }
  float Dc = block_reduce(acc, red);
  if (tid == 0) {
    float u_last = lY;
    float Su = Sy;
    float v_last = 0.5f / (kd * Su + u_last * (1.0f + 1e-6f));
    float D = Dc + delta * kd * (u_last * Sv + v_last * Su);
    out[0] = 2.0f * D;
    out[1] = 0.f;
    out[2] = 0.f;
    out[3] = 0.f;
  }
}

extern "C" void kernel_launch(void* const* d_in, const int* in_sizes, int n_in,
                              void* d_out, int out_size, void* d_ws, size_t ws_size,
                              hipStream_t stream) {
  const float* yp = (const float*)d_in[0];
  float* wsF = (float*)d_ws;
  int* wsI = (int*)d_ws;
  float* out = (float*)d_out;

  k_zero<<<32, 512, 0, stream>>>(wsI);
  k_hist<<<79, 512, 0, stream>>>(yp, wsI);
  k_findt<<<2, 1024, 0, stream>>>(wsI);
  k_cand<<<dim3(40, 2), 512, 0, stream>>>(yp, wsI, wsF);
  k_rankc<<<dim3(16, 16, 2), 512, 0, stream>>>(wsI, wsF, wsI);
  k_place<<<dim3(16, 2), 512, 0, stream>>>(wsI, wsF);
  k_solve<<<1, NTH, SOLVE_LDS_BYTES, stream>>>(wsF, out);
}

// Round 5
// 118.129 us; speedup vs baseline: 5.0097x; 5.0097x over previous
//
#include <hip/hip_runtime.h>

// Problem constants
#define HALF   20000
#define MSEL   6001        // top-30%: 20000 - int(0.7*20000)=13999 -> 6001
#define RANKLO 13999       // = HALF - MSEL
#define NBUCK  4096
#define CANDMAX 8192

// k_solve geometry: thread t owns contiguous elements [6t, 6t+6)
#define NTH   1024
#define TPT   6
#define NPAD  (NTH*TPT)    // 6144

// Workspace offsets (4-byte elements)
#define OFF_HIST   0        // int[2][4096]
#define OFF_TSEL   8192     // int[2]
#define OFF_CCNT   8194     // int[2]
#define OFF_ZERO_N 8196
#define OFF_CANDV  8704     // float[2][8192]
#define OFF_CANDI  25088    // int[2][8192]
#define OFF_RANK   41472    // int[2][8192]
#define OFF_XS     57856    // float[6016] sorted top of half0
#define OFF_YS     63872    // float[6016] sorted top of half1

// k_solve LDS layout (floats)
#define LPREF 0        // PrefA[6144] element-level exclusive prefix of A
#define LSUFB 6144     // SufB[6144]  element-level inclusive suffix of B
#define LCX   12288    // cx[6144]: xs at init, then c-vector for X targets
#define LCY   18432    // cy[6144]: ys at init, then c-vector for Y targets
#define LRED  24576    // red[64]
#define LSC   24640    // scal[16]
#define SOLVE_LDS_FLOATS 24656
#define SOLVE_LDS_BYTES (SOLVE_LDS_FLOATS * 4)

__device__ __forceinline__ float fexp2(float x) {
#if defined(__has_builtin)
#if __has_builtin(__builtin_amdgcn_exp2f)
  return __builtin_amdgcn_exp2f(x);
#else
  return exp2f(x);
#endif
#else
  return exp2f(x);
#endif
}

__device__ __forceinline__ int bucket_of(float v) {
  int b = (int)(v * 4096.0f);
  b = b < 0 ? 0 : b;
  b = b > (NBUCK - 1) ? (NBUCK - 1) : b;
  return b;
}

// ---------------- selection kernels (verified R2/R3) ----------------

__global__ __launch_bounds__(512) void k_zero(int* wsI) {
  int i = blockIdx.x * blockDim.x + threadIdx.x;
  if (i < OFF_ZERO_N) wsI[i] = 0;
  if (i < 2 * CANDMAX) wsI[OFF_RANK + i] = 0;
}

__global__ __launch_bounds__(512) void k_hist(const float* __restrict__ yp, int* wsI) {
  int i = blockIdx.x * blockDim.x + threadIdx.x;
  if (i >= 2 * HALF) return;
  int h = (i >= HALF) ? 1 : 0;
  atomicAdd(&wsI[OFF_HIST + h * NBUCK + bucket_of(yp[i])], 1);
}

__global__ __launch_bounds__(1024) void k_findt(int* wsI) {
  __shared__ int ss[1024];
  const int h = blockIdx.x;
  const int t = threadIdx.x;
  const int* hist = wsI + OFF_HIST + h * NBUCK;
  int c0 = hist[4 * t + 0], c1 = hist[4 * t + 1], c2 = hist[4 * t + 2], c3 = hist[4 * t + 3];
  ss[t] = c0 + c1 + c2 + c3;
  __syncthreads();
  for (int off = 1; off < 1024; off <<= 1) {
    int v = ss[t];
    if (t + off < 1024) v += ss[t + off];
    __syncthreads();
    ss[t] = v;
    __syncthreads();
  }
  int SSnext = (t < 1023) ? ss[t + 1] : 0;
  int R3 = c3 + SSnext;
  int R2 = c2 + R3;
  int R1 = c1 + R2;
  int R0 = c0 + R1;
  if (R0 >= MSEL && R1 < MSEL) wsI[OFF_TSEL + h] = 4 * t + 0;
  if (R1 >= MSEL && R2 < MSEL) wsI[OFF_TSEL + h] = 4 * t + 1;
  if (R2 >= MSEL && R3 < MSEL) wsI[OFF_TSEL + h] = 4 * t + 2;
  if (R3 >= MSEL && SSnext < MSEL) wsI[OFF_TSEL + h] = 4 * t + 3;
}

__global__ __launch_bounds__(512) void k_cand(const float* __restrict__ yp, int* wsI, float* wsF) {
  __shared__ int ss[512];
  __shared__ int sbase;
  const int h = blockIdx.y;
  const int tid = threadIdx.x;
  const int idx = blockIdx.x * 512 + tid;
  float v = 0.f;
  int flag = 0;
  if (idx < HALF) {
    v = yp[h * HALF + idx];
    flag = (bucket_of(v) >= wsI[OFF_TSEL + h]) ? 1 : 0;
  }
  ss[tid] = flag;
  __syncthreads();
  for (int off = 1; off < 512; off <<= 1) {
    int add = (tid >= off) ? ss[tid - off] : 0;
    __syncthreads();
    ss[tid] += add;
    __syncthreads();
  }
  if (tid == 511) sbase = atomicAdd(&wsI[OFF_CCNT + h], ss[511]);
  __syncthreads();
  if (flag) {
    int pos = sbase + ss[tid] - 1;
    if (pos < CANDMAX) {
      wsF[OFF_CANDV + h * CANDMAX + pos] = v;
      wsI[OFF_CANDI + h * CANDMAX + pos] = idx;
    }
  }
}

__global__ __launch_bounds__(512) void k_rankc(const int* __restrict__ wsIc, float* wsF, int* wsI) {
  __shared__ float cv[512];
  __shared__ int ci[512];
  const int h = blockIdx.z;
  const int tid = threadIdx.x;
  const int cnt = min(wsIc[OFF_CCNT + h], CANDMAX);
  const int cb = blockIdx.y * 512;
  if (cb >= cnt) return;
  const int clen = min(512, cnt - cb);
  if (tid < clen) {
    cv[tid] = wsF[OFF_CANDV + h * CANDMAX + cb + tid];
    ci[tid] = wsIc[OFF_CANDI + h * CANDMAX + cb + tid];
  }
  __syncthreads();
  const int g = blockIdx.x * 512 + tid;
  if (g >= cnt) return;
  const float v = wsF[OFF_CANDV + h * CANDMAX + g];
  const int li = wsIc[OFF_CANDI + h * CANDMAX + g];
  int r = 0;
  for (int l = 0; l < clen; ++l) {
    float w = cv[l];
    r += (w < v || (w == v && ci[l] < li)) ? 1 : 0;
  }
  atomicAdd(&wsI[OFF_RANK + h * CANDMAX + g], r);
}

__global__ __launch_bounds__(512) void k_place(const int* __restrict__ wsI, float* wsF) {
  const int h = blockIdx.y;
  const int g = blockIdx.x * 512 + threadIdx.x;
  const int cnt = min(wsI[OFF_CCNT + h], CANDMAX);
  if (g >= cnt) return;
  const int full = wsI[OFF_RANK + h * CANDMAX + g] + (HALF - cnt);
  if (full >= RANKLO) {
    wsF[(h ? OFF_YS : OFF_XS) + (full - RANKLO)] = wsF[OFF_CANDV + h * CANDMAX + g];
  }
}

// ---------------- persistent Sinkhorn solver (single block) ----------------

__device__ __forceinline__ float block_reduce(float v, float* red) {
  const int tid = threadIdx.x;
  __syncthreads();
  for (int d = 1; d < 64; d <<= 1) v += __shfl_xor(v, d, 64);
  if ((tid & 63) == 0) red[tid >> 6] = v;
  __syncthreads();
  float r = 0.f;
  if (tid < 16) {
    r = red[tid];
    for (int d = 1; d < 16; d <<= 1) r += __shfl_xor(r, d, 16);
    if (tid == 0) red[0] = r;
  }
  __syncthreads();
  return red[0];
}

__device__ __forceinline__ int bsearch(const float* arr, float v) {
  int lo = 0, hi = MSEL;
  while (lo < hi) {
    int m = (lo + hi) >> 1;
    if (arr[m] <= v) lo = m + 1; else hi = m;
  }
  return lo;
}

// Full element-level scan: PrefA[j] = sum_{k<j} a_k (exclusive),
// SufB[j] = sum_{k>=j} b_k (inclusive). totA -> red[48], totW -> red[49].
// Optional scalar-state update (done by tid 0 between internal barriers).
__device__ __forceinline__ void scan_ab(const float (&a)[TPT], const float (&b)[TPT],
                                        float wsum, float* lds,
                                        int do_state, int sout, int lout, float lnext) {
  float* PrefA = lds + LPREF;
  float* SufB = lds + LSUFB;
  float* red = lds + LRED;
  float* scal = lds + LSC;
  const int tid = threadIdx.x;
  const int wv = tid >> 6, ln = tid & 63;
  float pa[TPT], sb[TPT];
  float ta = 0.f;
#pragma unroll
  for (int k = 0; k < TPT; ++k) { pa[k] = ta; ta += a[k]; }
  float tb = 0.f;
#pragma unroll
  for (int k = TPT - 1; k >= 0; --k) { tb += b[k]; sb[k] = tb; }
  float ia = ta, ib = tb, iw = wsum;
#pragma unroll
  for (int d = 1; d < 64; d <<= 1) {
    float oa = __shfl_up(ia, d, 64);
    float ob = __shfl_down(ib, d, 64);
    float ow = __shfl_xor(iw, d, 64);
    if (ln >= d) ia += oa;
    if (ln + d < 64) ib += ob;
    iw += ow;
  }
  if (ln == 63) red[wv] = ia;
  if (ln == 0) { red[16 + wv] = ib; red[32 + wv] = iw; }
  __syncthreads();
  if (tid < 16) {
    float wa = red[tid], wb = red[16 + tid], ww = red[32 + tid];
    float sa = wa, sbw = wb, sw = ww;
#pragma unroll
    for (int d = 1; d < 16; d <<= 1) {
      float oa = __shfl_up(sa, d, 16);
      float ob = __shfl_down(sbw, d, 16);
      float ow = __shfl_xor(sw, d, 16);
      if (tid >= d) sa += oa;
      if (tid + d < 16) sbw += ob;
      sw += ow;
    }
    red[tid] = sa - wa;        // per-wave exclusive prefix offset (A)
    red[16 + tid] = sbw - wb;  // per-wave exclusive suffix offset (B)
    if (tid == 15) red[48] = sa;  // total A
    if (tid == 0) {
      red[49] = sw;               // total W
      if (do_state) { scal[sout] = sw; scal[lout] = lnext; }
    }
  }
  __syncthreads();
  const float GA = red[wv] + (ia - ta);
  const float GB = red[16 + wv] + (ib - tb);
  const int base = tid * TPT;
#pragma unroll
  for (int k = 0; k < TPT; ++k) {
    PrefA[base + k] = GA + pa[k];
    SufB[base + k] = GB + sb[k];
  }
  __syncthreads();
}

// One Sinkhorn pass. SA/SB = source exps (+/-), TA/TB = target exps (+/-),
// tp = merge positions of targets in the source array.
// mode 0: uniform au weights; 1: first stateful pass; 2: steady state.
__device__ __forceinline__ void do_pass(float* lds, const float* zin, float* zout,
                                        const float (&SA)[TPT], const float (&SB)[TPT],
                                        const float (&TA)[TPT], const float (&TB)[TPT],
                                        const int (&tp)[TPT],
                                        int mode, int sin, int lin, int sout, int lout) {
  float* PrefA = lds + LPREF;
  float* SufB = lds + LSUFB;
  float* scal = lds + LSC;
  const int tid = threadIdx.x;
  const int base = tid * TPT;
  const float au = 0.5f / 20000.0f;
  const float kd = scal[2];
  float S_in = 0.f, l_in = 0.f, cin = 0.f, lnext = 0.f;
  if (mode == 1) { S_in = (float)MSEL * au; l_in = 0.5f; }
  else if (mode == 2) { S_in = scal[sin]; l_in = scal[lin]; }
  if (mode) {
    cin = 1e-6f * S_in + l_in * kd;
    lnext = 0.5f / (kd * S_in + l_in * (1.0f + 1e-6f));
  }
  float a[TPT], b[TPT];
  float wsum = 0.f;
#pragma unroll
  for (int k = 0; k < TPT; ++k) {
    int j = base + k;
    float w = 0.f;
    if (j < MSEL) w = mode ? (au / (zin[j] + cin)) : au;
    wsum += w;
    a[k] = w * SA[k];
    b[k] = w * SB[k];
  }
  scan_ab(a, b, wsum, lds, mode != 0, sout, lout, lnext);
#pragma unroll
  for (int k = 0; k < TPT; ++k) {
    int i = base + k;
    if (i < MSEL) {
      int p = tp[k];
      zout[i] = TB[k] * PrefA[p] + TA[k] * SufB[p];
    }
  }
}

__global__ __launch_bounds__(NTH) void k_solve(float* __restrict__ wsF, float* __restrict__ out) {
  extern __shared__ float lds[];
  const int tid = threadIdx.x;
  float* PrefA = lds + LPREF;
  float* SufB = lds + LSUFB;
  float* cx = lds + LCX;
  float* cy = lds + LCY;
  float* red = lds + LRED;
  float* scal = lds + LSC;
  const float au = 0.5f / 20000.0f;
  const int base = tid * TPT;

  // load sorted arrays into cx/cy (pad 1e30 for search safety)
#pragma unroll
  for (int k = 0; k < TPT; ++k) {
    int j = base + k;
    cx[j] = (j < MSEL) ? wsF[OFF_XS + j] : 1e30f;
    cy[j] = (j < MSEL) ? wsF[OFF_YS + j] : 1e30f;
  }
  __syncthreads();

  // per-thread values + merge positions (bsearch for k=0, short walk after)
  float xr[TPT], yr[TPT];
  int px[TPT], py[TPT];
#pragma unroll
  for (int k = 0; k < TPT; ++k) {
    int j = base + k;
    xr[k] = (j < MSEL) ? cx[j] : 0.f;
    yr[k] = (j < MSEL) ? cy[j] : 0.f;
  }
  {
    int p = bsearch(cy, xr[0]);
    px[0] = p;
#pragma unroll
    for (int k = 1; k < TPT; ++k) {
      float x = xr[k];
      while (cy[p] <= x) ++p;
      px[k] = p;
    }
    int q = bsearch(cx, yr[0]);
    py[0] = q;
#pragma unroll
    for (int k = 1; k < TPT; ++k) {
      float y = yr[k];
      while (cx[q] <= y) ++q;
      py[k] = q;
    }
  }

  // meanM: sum_j |x - y_j| = x(2p-m) + PyT - 2*Py(p)
  {
    float a0[TPT], b0[TPT];
#pragma unroll
    for (int k = 0; k < TPT; ++k) { a0[k] = yr[k]; b0[k] = 0.f; }
    scan_ab(a0, b0, 0.f, lds, 0, 0, 0, 0.f);
    const float PyT = red[48];
    float rs = 0.f;
#pragma unroll
    for (int k = 0; k < TPT; ++k) {
      int i = base + k;
      if (i < MSEL)
        rs += xr[k] * (float)(2 * px[k] - MSEL) + PyT - 2.f * PrefA[px[k]];
    }
    float tot = block_reduce(rs, red);
    if (tid == 0) {
      float meanM = tot / ((float)MSEL * (float)MSEL);
      float lam = 10.0f / meanM;
      float lamL2 = lam * 1.4426950408889634f;
      float delta = fmaxf(cy[MSEL - 1] - cx[0], cx[MSEL - 1] - cy[0]);
      float kd = fexp2(-lamL2 * delta) + 1e-6f;
      float lo = fminf(cx[0], cy[0]);
      float hi = fmaxf(cx[MSEL - 1], cy[MSEL - 1]);
      scal[0] = lamL2;
      scal[1] = delta;
      scal[2] = kd;
      scal[3] = 0.5f * (lo + hi);
    }
  }
  __syncthreads();

  // precompute all exps once (lambda fixed): passes contain no transcendentals
  const float lamL2 = scal[0];
  const float mid = scal[3];
  float EAx[TPT], EBx[TPT], EAy[TPT], EBy[TPT];
#pragma unroll
  for (int k = 0; k < TPT; ++k) {
    int j = base + k;
    if (j < MSEL) {
      float X = lamL2 * (xr[k] - mid);
      EAx[k] = fexp2(X);
      EBx[k] = fexp2(-X);
      float Y = lamL2 * (yr[k] - mid);
      EAy[k] = fexp2(Y);
      EBy[k] = fexp2(-Y);
    } else {
      EAx[k] = EBx[k] = EAy[k] = EBy[k] = 0.f;
    }
  }

  // Sinkhorn chain: scal slots 4=Sx, 5=Sy, 6=lX, 7=lY
  do_pass(lds, cx, cx, EAy, EBy, EAx, EBx, px, 0, 0, 0, 0, 0);
  for (int it = 0; it < 10; ++it) {
    do_pass(lds, cx, cy, EAx, EBx, EAy, EBy, py, (it == 0) ? 1 : 2, 5, 7, 4, 6);
    do_pass(lds, cy, cx, EAy, EBy, EAx, EBx, px, 2, 4, 6, 5, 7);
  }

  // D-pass (3 scan sub-phases, identical math to validated R4)
  const float delta = scal[1], kd2 = scal[2];
  const float Sx = scal[4], Sy = scal[5], lX = scal[6], lY = scal[7];
  const float cin_v = 1e-6f * Sy + lY * kd2;
  const float cin_u = 1e-6f * Sx + lX * kd2;

  float v[TPT];
  float sv = 0.f, svx = 0.f;
#pragma unroll
  for (int k = 0; k < TPT; ++k) {
    int j = base + k;
    if (j < MSEL) {
      v[k] = au / (cx[j] + cin_v);
      sv += v[k];
      svx += v[k] * xr[k];
    } else v[k] = 0.f;
  }
  const float Sv = block_reduce(sv, red);
  const float TVX = block_reduce(svx, red);

  float dvk[TPT];
  float aa[TPT], bb[TPT];
  // sub1: a=v*2^X, b=v*2^-X  ->  y*(e^-Y * P1 - e^+Y * S1)
#pragma unroll
  for (int k = 0; k < TPT; ++k) { aa[k] = v[k] * EAx[k]; bb[k] = v[k] * EBx[k]; }
  scan_ab(aa, bb, 0.f, lds, 0, 0, 0, 0.f);
#pragma unroll
  for (int k = 0; k < TPT; ++k) {
    int i = base + k;
    if (i < MSEL) {
      int p = py[k];
      dvk[k] = yr[k] * (EBy[k] * PrefA[p] - EAy[k] * SufB[p]);
    } else dvk[k] = 0.f;
  }
  // sub2: a=v*x*2^X, b=v*x*2^-X  ->  -e^-Y * P2 + e^+Y * S2
#pragma unroll
  for (int k = 0; k < TPT; ++k) { aa[k] *= xr[k]; bb[k] *= xr[k]; }
  scan_ab(aa, bb, 0.f, lds, 0, 0, 0, 0.f);
#pragma unroll
  for (int k = 0; k < TPT; ++k) {
    int i = base + k;
    if (i < MSEL) {
      int p = py[k];
      dvk[k] += -EBy[k] * PrefA[p] + EAy[k] * SufB[p];
    }
  }
  // sub3: a=v, b=v*x  ->  1e-6*( y*(2*P5 - Sv) + 2*S6 - TVX )
#pragma unroll
  for (int k = 0; k < TPT; ++k) { aa[k] = v[k]; bb[k] = v[k] * xr[k]; }
  scan_ab(aa, bb, 0.f, lds, 0, 0, 0, 0.f);
  float acc = 0.f;
#pragma unroll
  for (int k = 0; k < TPT; ++k) {
    int i = base + k;
    if (i < MSEL) {
      int p = py[k];
      float d6 = dvk[k] + 1e-6f * (yr[k] * (2.f * PrefA[p] - Sv) + 2.f * SufB[p] - TVX);
      float u = au / (cy[i] + cin_u);
      acc += u * d6;
    }
  }
  float Dc = block_reduce(acc, red);
  if (tid == 0) {
    float v_last = 0.5f / (kd2 * Sy + lY * (1.0f + 1e-6f));
    float D = Dc + delta * kd2 * (lY * Sv + v_last * Sy);
    out[0] = 2.0f * D;
    out[1] = 0.f;
    out[2] = 0.f;
    out[3] = 0.f;
  }
}

extern "C" void kernel_launch(void* const* d_in, const int* in_sizes, int n_in,
                              void* d_out, int out_size, void* d_ws, size_t ws_size,
                              hipStream_t stream) {
  const float* yp = (const float*)d_in[0];
  float* wsF = (float*)d_ws;
  int* wsI = (int*)d_ws;
  float* out = (float*)d_out;

  k_zero<<<32, 512, 0, stream>>>(wsI);
  k_hist<<<79, 512, 0, stream>>>(yp, wsI);
  k_findt<<<2, 1024, 0, stream>>>(wsI);
  k_cand<<<dim3(40, 2), 512, 0, stream>>>(yp, wsI, wsF);
  k_rankc<<<dim3(16, 16, 2), 512, 0, stream>>>(wsI, wsF, wsI);
  k_place<<<dim3(16, 2), 512, 0, stream>>>(wsI, wsF);
  k_solve<<<1, NTH, SOLVE_LDS_BYTES, stream>>>(wsF, out);
}

// Round 8
// 101.743 us; speedup vs baseline: 5.8165x; 1.1611x over previous
//
#include <hip/hip_runtime.h>

// Problem constants
#define HALF   20000
#define MSEL   6001        // top-30%: 20000 - int(0.7*20000)=13999 -> 6001
#define RANKLO 13999       // = HALF - MSEL
#define NBUCK  4096
#define CANDMAX 8192

// k_solve geometry: thread t owns contiguous elements [8t, 8t+8)
#define NTH   768
#define TPT   8
#define NPAD  (NTH*TPT)    // 6144
#define NWAVE 12

// Workspace offsets (4-byte elements)
#define OFF_HIST   0        // int[2][4096]
#define OFF_CCNT   8192     // int[2]
#define OFF_RANK   8704     // int[2][8192]
#define OFF_CANDV  25088    // float[2][8192]
#define OFF_CANDI  41472    // int[2][8192]
#define ZERO_BYTES (25088*4)  // hist + ccnt + rank

// k_solve LDS layout (floats)
#define LPREF 0        // PrefA[6144] (also xs during init)
#define LSUFB 6144     // SufB[6144]  (also ys during init)
#define LRED  12288    // red[64]
#define LSC   12352    // scal[16]
#define SOLVE_LDS_FLOATS 12368
#define SOLVE_LDS_BYTES (SOLVE_LDS_FLOATS * 4)

__device__ __forceinline__ float fexp2(float x) {
#if defined(__has_builtin)
#if __has_builtin(__builtin_amdgcn_exp2f)
  return __builtin_amdgcn_exp2f(x);
#else
  return exp2f(x);
#endif
#else
  return exp2f(x);
#endif
}

__device__ __forceinline__ float frcp(float x) {
#if defined(__has_builtin)
#if __has_builtin(__builtin_amdgcn_rcpf)
  return __builtin_amdgcn_rcpf(x);
#else
  return 1.0f / x;
#endif
#else
  return 1.0f / x;
#endif
}

#if defined(__has_builtin)
#if __has_builtin(__builtin_amdgcn_update_dpp) && __has_builtin(__builtin_amdgcn_readlane)
#define HAS_DPP 1
#endif
#endif

#ifdef HAS_DPP
template<int CTRL, int RM>
__device__ __forceinline__ float dppadd(float x) {
  int s = __builtin_amdgcn_update_dpp(0, __float_as_int(x), CTRL, RM, 0xf, false);
  return x + __int_as_float(s);
}
// inclusive 64-lane prefix sum (classic gfx9 sequence)
__device__ __forceinline__ float prefix64(float x) {
  x = dppadd<0x111, 0xf>(x);   // row_shr:1
  x = dppadd<0x112, 0xf>(x);   // row_shr:2
  x = dppadd<0x114, 0xf>(x);   // row_shr:4
  x = dppadd<0x118, 0xf>(x);   // row_shr:8
  x = dppadd<0x142, 0xa>(x);   // row_bcast:15 -> rows 1,3
  x = dppadd<0x143, 0xc>(x);   // row_bcast:31 -> rows 2,3
  return x;
}
// inclusive prefix within a 16-lane row
__device__ __forceinline__ float prefixrow(float x) {
  x = dppadd<0x111, 0xf>(x);
  x = dppadd<0x112, 0xf>(x);
  x = dppadd<0x114, 0xf>(x);
  x = dppadd<0x118, 0xf>(x);
  return x;
}
// inclusive suffix within a 16-lane row (row_shl: lane n reads lane n+d)
__device__ __forceinline__ float sufrow(float x) {
  x = dppadd<0x101, 0xf>(x);
  x = dppadd<0x102, 0xf>(x);
  x = dppadd<0x104, 0xf>(x);
  x = dppadd<0x108, 0xf>(x);
  return x;
}
__device__ __forceinline__ float rdlane(float x, int l) {
  return __int_as_float(__builtin_amdgcn_readlane(__float_as_int(x), l));
}
#else
__device__ __forceinline__ float prefix64(float x) {
  for (int d = 1; d < 64; d <<= 1) {
    float o = __shfl_up(x, d, 64);
    if ((threadIdx.x & 63) >= d) x += o;
  }
  return x;
}
__device__ __forceinline__ float prefixrow(float x) {
  for (int d = 1; d < 16; d <<= 1) {
    float o = __shfl_up(x, d, 64);
    if ((threadIdx.x & 15) >= d) x += o;
  }
  return x;
}
__device__ __forceinline__ float sufrow(float x) {
  for (int d = 1; d < 16; d <<= 1) {
    float o = __shfl_down(x, d, 64);
    if ((threadIdx.x & 15) + d < 16) x += o;
  }
  return x;
}
__device__ __forceinline__ float rdlane(float x, int l) { return __shfl(x, l, 64); }
#endif

__device__ __forceinline__ int bucket_of(float v) {
  int b = (int)(v * 4096.0f);
  b = b < 0 ? 0 : b;
  b = b > (NBUCK - 1) ? (NBUCK - 1) : b;
  return b;
}

// ---------------- selection kernels ----------------

__global__ __launch_bounds__(512) void k_hist(const float* __restrict__ yp, int* wsI) {
  int i = blockIdx.x * blockDim.x + threadIdx.x;
  if (i >= 2 * HALF) return;
  int h = (i >= HALF) ? 1 : 0;
  atomicAdd(&wsI[OFF_HIST + h * NBUCK + bucket_of(yp[i])], 1);
}

// candidate compaction with fused threshold-bucket search
__global__ __launch_bounds__(512) void k_cand(const float* __restrict__ yp, int* wsI, float* wsF) {
  __shared__ int ss[512];
  __shared__ int sboundary;
  __shared__ int sbase;
  const int h = blockIdx.y;
  const int tid = threadIdx.x;

  // --- fused findt: thread owns buckets [8t, 8t+8)
  int c[8];
  int tot = 0;
#pragma unroll
  for (int q = 0; q < 8; ++q) {
    c[q] = wsI[OFF_HIST + h * NBUCK + tid * 8 + q];
    tot += c[q];
  }
  if (tid == 0) sboundary = -1;
  ss[tid] = tot;
  __syncthreads();
  for (int off = 1; off < 512; off <<= 1) {
    int add = (tid >= off) ? ss[tid - off] : 0;
    __syncthreads();
    ss[tid] += add;
    __syncthreads();
  }
  const int total = ss[511];
  const int suffAfter = total - ss[tid];  // elements in buckets of threads > tid
  int run = suffAfter;
  int best = -1;
#pragma unroll
  for (int q = 7; q >= 0; --q) {
    run += c[q];
    if (best < 0 && run >= MSEL) best = tid * 8 + q;  // largest b with R(b) >= MSEL
  }
  if (best >= 0) atomicMax(&sboundary, best);
  __syncthreads();
  const int tsel = sboundary;

  // --- candidate flag + block compaction
  const int idx = blockIdx.x * 512 + tid;
  float v = 0.f;
  int flag = 0;
  if (idx < HALF) {
    v = yp[h * HALF + idx];
    flag = (bucket_of(v) >= tsel) ? 1 : 0;
  }
  __syncthreads();
  ss[tid] = flag;
  __syncthreads();
  for (int off = 1; off < 512; off <<= 1) {
    int add = (tid >= off) ? ss[tid - off] : 0;
    __syncthreads();
    ss[tid] += add;
    __syncthreads();
  }
  if (tid == 511) sbase = atomicAdd(&wsI[OFF_CCNT + h], ss[511]);
  __syncthreads();
  if (flag) {
    int pos = sbase + ss[tid] - 1;
    if (pos < CANDMAX) {
      wsF[OFF_CANDV + h * CANDMAX + pos] = v;
      wsI[OFF_CANDI + h * CANDMAX + pos] = idx;
    }
  }
}

// rank among candidates (all below-threshold elements are strictly smaller)
__global__ __launch_bounds__(512) void k_rankc(const int* __restrict__ wsIc, float* wsF, int* wsI) {
  __shared__ float cv[512];
  __shared__ int ci[512];
  const int h = blockIdx.z;
  const int tid = threadIdx.x;
  const int cnt = min(wsIc[OFF_CCNT + h], CANDMAX);
  const int cb = blockIdx.y * 512;
  if (cb >= cnt) return;
  const int clen = min(512, cnt - cb);
  if (tid < clen) {
    cv[tid] = wsF[OFF_CANDV + h * CANDMAX + cb + tid];
    ci[tid] = wsIc[OFF_CANDI + h * CANDMAX + cb + tid];
  }
  __syncthreads();
  const int g = blockIdx.x * 512 + tid;
  if (g >= cnt) return;
  const float v = wsF[OFF_CANDV + h * CANDMAX + g];
  const int li = wsIc[OFF_CANDI + h * CANDMAX + g];
  int r = 0;
  for (int l = 0; l < clen; ++l) {
    float w = cv[l];
    r += (w < v || (w == v && ci[l] < li)) ? 1 : 0;
  }
  atomicAdd(&wsI[OFF_RANK + h * CANDMAX + g], r);
}

// ---------------- persistent Sinkhorn solver (single block) ----------------

// NOTE: only NWAVE (=12) waves exist; red[NWAVE..15] are never written by the
// partial-store step, so the second stage MUST mask them (R7 bug: read garbage).
__device__ __forceinline__ float block_reduce(float v, float* red) {
  const int tid = threadIdx.x;
  __syncthreads();
  for (int d = 1; d < 64; d <<= 1) v += __shfl_xor(v, d, 64);
  if ((tid & 63) == 0) red[tid >> 6] = v;
  __syncthreads();
  float r = 0.f;
  if (tid < 16) {
    r = (tid < NWAVE) ? red[tid] : 0.f;
    for (int d = 1; d < 16; d <<= 1) r += __shfl_xor(r, d, 16);
    if (tid == 0) red[0] = r;
  }
  __syncthreads();
  return red[0];
}

__device__ __forceinline__ int bsearch(const float* arr, float v) {
  int lo = 0, hi = MSEL;
  while (lo < hi) {
    int m = (lo + hi) >> 1;
    if (arr[m] <= v) lo = m + 1; else hi = m;
  }
  return lo;
}

// Element-level scans, ALL ADDITION-ONLY (values span ~2^+-28; any
// total-minus-prefix subtraction is catastrophic — R6 lesson).
// PrefA[j] = sum_{k<j} a_k (exclusive), SufB[j] = sum_{k>=j} b_k (inclusive).
// Block total of A -> red[48]. Optional state write by tid 0.
template<bool DO_W>
__device__ __forceinline__ void scan_ab(const float (&a)[TPT], const float (&b)[TPT],
                                        float wsum, float* lds,
                                        int sout, int lout, float lnext) {
  float* PrefA = lds + LPREF;
  float* SufB  = lds + LSUFB;
  float* red   = lds + LRED;
  float* scal  = lds + LSC;
  const int tid = threadIdx.x;
  const int wv = tid >> 6, ln = tid & 63;
  // thread-local exclusive prefix / inclusive suffix (direct accumulation)
  float pa[TPT], sb[TPT];
  float ta = 0.f;
#pragma unroll
  for (int k = 0; k < TPT; ++k) { pa[k] = ta; ta += a[k]; }
  float tb = 0.f;
#pragma unroll
  for (int k = TPT - 1; k >= 0; --k) { tb += b[k]; sb[k] = tb; }

  // wave-level A: exclusive prefix via shift-then-inclusive-scan
  float tsA = __shfl_up(ta, 1, 64);
  if (ln == 0) tsA = 0.f;
  const float eA = prefix64(tsA);                 // sum_{l<ln} ta_l
  const float wTotA = rdlane(eA, 63) + rdlane(ta, 63);

  // wave-level B: exclusive suffix via shift-then-row-suffix + row totals
  float tsB = __shfl_down(tb, 1, 64);
  if (ln == 63) tsB = 0.f;
  const float sRow = sufrow(tsB);                 // within-row inclusive suffix of shifted
  const float r1 = rdlane(sRow, 16);
  const float r2 = rdlane(sRow, 32);
  const float r3 = rdlane(sRow, 48);
  const int row = ln >> 4;
  const float radd = (row == 0) ? (r1 + r2 + r3)
                   : (row == 1) ? (r2 + r3)
                   : (row == 2) ? r3 : 0.f;
  const float eB = sRow + radd;                   // sum_{l>ln} tb_l
  const float wTotB = rdlane(eB, 0) + rdlane(tb, 0);

  float wTotW = 0.f;
  if (DO_W) {
    float iW = prefix64(wsum);
    wTotW = rdlane(iW, 63);
  }
  if (ln == 0) {
    red[wv] = wTotA;
    red[16 + wv] = wTotB;
    if (DO_W) red[32 + wv] = wTotW;
  }
  __syncthreads();
  // cross-wave combine (redundant in every wave), addition-only:
  // A: load wave totals shifted by one -> inclusive prefixrow = exclusive prefix
  float tAs = (ln >= 1 && ln <= NWAVE) ? red[ln - 1] : 0.f;
  const float pAe = prefixrow(tAs);               // lane j: sum of wave totals < j; lane NWAVE = block total
  const float GAoff = rdlane(pAe, wv);
  // B: load reversed -> inclusive prefixrow = suffix; lane (NWAVE-2-wv) = sum over waves > wv
  float tBr = (ln < NWAVE) ? red[16 + (NWAVE - 1 - ln)] : 0.f;
  const float pBr = prefixrow(tBr);
  const float GBoff = (wv < NWAVE - 1) ? rdlane(pBr, (NWAVE - 2) - wv) : 0.f;
  if (tid == 0) {
    red[48] = rdlane(pAe, NWAVE);                 // block total of A
    if (DO_W) {
      float s = 0.f;
#pragma unroll
      for (int q = 0; q < NWAVE; ++q) s += red[32 + q];
      scal[sout] = s;
      scal[lout] = lnext;
    }
  }
  // element-level write-out (2x b128 per array)
  const float GA = GAoff + eA;
  const float GB = GBoff + eB;
  const int base = tid * TPT;
  float4* pp = (float4*)(PrefA + base);
  float4* sp = (float4*)(SufB + base);
  pp[0] = make_float4(GA + pa[0], GA + pa[1], GA + pa[2], GA + pa[3]);
  pp[1] = make_float4(GA + pa[4], GA + pa[5], GA + pa[6], GA + pa[7]);
  sp[0] = make_float4(GB + sb[0], GB + sb[1], GB + sb[2], GB + sb[3]);
  sp[1] = make_float4(GB + sb[4], GB + sb[5], GB + sb[6], GB + sb[7]);
  __syncthreads();
}

// One Sinkhorn pass; z carried in registers (thread owns same elements on both sides).
// MODE 0: uniform au weights; 1: first stateful pass (constants); 2: steady state.
template<int MODE>
__device__ __forceinline__ void do_pass(float* lds,
    const float (&zin)[TPT], float (&zout)[TPT],
    const float (&SA)[TPT], const float (&SB)[TPT],
    const float (&TA)[TPT], const float (&TB)[TPT],
    const int (&tp)[TPT], int sin, int lin, int sout, int lout) {
  float* PrefA = lds + LPREF;
  float* SufB  = lds + LSUFB;
  float* scal  = lds + LSC;
  const int base = threadIdx.x * TPT;
  const float au = 0.5f / 20000.0f;
  float cin = 0.f, lnext = 0.f;
  if (MODE) {
    const float kd = scal[2];
    float S_in, l_in;
    if (MODE == 1) { S_in = (float)MSEL * au; l_in = 0.5f; }
    else { S_in = scal[sin]; l_in = scal[lin]; }
    cin = 1e-6f * S_in + l_in * kd;
    lnext = 0.5f * frcp(kd * S_in + l_in * (1.0f + 1e-6f));
  }
  float a[TPT], b[TPT];
  float wsum = 0.f;
#pragma unroll
  for (int k = 0; k < TPT; ++k) {
    float w = 0.f;
    if (base + k < MSEL) w = MODE ? au * frcp(zin[k] + cin) : au;
    wsum += w;
    a[k] = w * SA[k];
    b[k] = w * SB[k];
  }
  scan_ab<(MODE != 0)>(a, b, wsum, lds, sout, lout, lnext);
#pragma unroll
  for (int k = 0; k < TPT; ++k) {
    int p = tp[k];
    zout[k] = (base + k < MSEL) ? (TB[k] * PrefA[p] + TA[k] * SufB[p]) : 0.f;
  }
}

__global__ __launch_bounds__(NTH) void k_solve(const float* __restrict__ wsF,
                                               const int* __restrict__ wsI,
                                               float* __restrict__ out) {
  extern __shared__ float lds[];
  const int tid = threadIdx.x;
  float* xs  = lds + LPREF;  // aliases: raw sorted values during init
  float* ys  = lds + LSUFB;
  float* red = lds + LRED;
  float* scal = lds + LSC;
  const float au = 0.5f / 20000.0f;
  const int base = tid * TPT;

  // init: pad everything with 1e30, zero the red/scal scratch, then scatter
  {
    float4 big = make_float4(1e30f, 1e30f, 1e30f, 1e30f);
    ((float4*)(xs + base))[0] = big;
    ((float4*)(xs + base))[1] = big;
    ((float4*)(ys + base))[0] = big;
    ((float4*)(ys + base))[1] = big;
    if (tid < 80) lds[LRED + tid] = 0.f;   // red[64] + scal[16]
  }
  __syncthreads();
  for (int h = 0; h < 2; ++h) {
    const int cnt = min(wsI[OFF_CCNT + h], CANDMAX);
    float* dst = h ? ys : xs;
    for (int c = tid; c < cnt; c += NTH) {
      int full = wsI[OFF_RANK + h * CANDMAX + c] + (HALF - cnt);
      if (full >= RANKLO) dst[full - RANKLO] = wsF[OFF_CANDV + h * CANDMAX + c];
    }
  }
  __syncthreads();

  // own values (pads -> 0) + boundary values for tid0
  float xr[TPT], yr[TPT];
  {
    float4 x0 = ((float4*)(xs + base))[0], x1 = ((float4*)(xs + base))[1];
    float4 y0 = ((float4*)(ys + base))[0], y1 = ((float4*)(ys + base))[1];
    float tx[TPT] = {x0.x, x0.y, x0.z, x0.w, x1.x, x1.y, x1.z, x1.w};
    float ty[TPT] = {y0.x, y0.y, y0.z, y0.w, y1.x, y1.y, y1.z, y1.w};
#pragma unroll
    for (int k = 0; k < TPT; ++k) {
      xr[k] = (base + k < MSEL) ? tx[k] : 0.f;
      yr[k] = (base + k < MSEL) ? ty[k] : 0.f;
    }
  }
  float bx0 = 0.f, bxl = 0.f, by0 = 0.f, byl = 0.f;
  if (tid == 0) {
    bx0 = xs[0]; bxl = xs[MSEL - 1];
    by0 = ys[0]; byl = ys[MSEL - 1];
  }
  // merge positions (lambda-independent)
  int px[TPT], py[TPT];
#pragma unroll
  for (int k = 0; k < TPT; ++k) { px[k] = 0; py[k] = 0; }
  if (base < MSEL) {
    int p = bsearch(ys, xr[0]);
    px[0] = p;
#pragma unroll
    for (int k = 1; k < TPT; ++k) {
      float x = xr[k];
      while (ys[p] <= x) ++p;
      px[k] = p;
    }
    int q = bsearch(xs, yr[0]);
    py[0] = q;
#pragma unroll
    for (int k = 1; k < TPT; ++k) {
      float y = yr[k];
      while (xs[q] <= y) ++q;
      py[k] = q;
    }
  }

  // meanM: sum_j |x - y_j| = x(2p-m) + PyT - 2*Py(p)
  {
    float a0[TPT], b0[TPT];
#pragma unroll
    for (int k = 0; k < TPT; ++k) { a0[k] = yr[k]; b0[k] = 0.f; }
    scan_ab<false>(a0, b0, 0.f, lds, 0, 0, 0.f);
    float* PrefA = lds + LPREF;
    const float PyT = red[48];
    float rs = 0.f;
#pragma unroll
    for (int k = 0; k < TPT; ++k) {
      if (base + k < MSEL)
        rs += xr[k] * (float)(2 * px[k] - MSEL) + PyT - 2.f * PrefA[px[k]];
    }
    float tot = block_reduce(rs, red);
    if (tid == 0) {
      float meanM = tot / ((float)MSEL * (float)MSEL);
      float lam = 10.0f / meanM;
      float lamL2 = lam * 1.4426950408889634f;
      float delta = fmaxf(byl - bx0, bxl - by0);
      float kd = fexp2(-lamL2 * delta) + 1e-6f;
      float lo = fminf(bx0, by0);
      float hi = fmaxf(bxl, byl);
      scal[0] = lamL2;
      scal[1] = delta;
      scal[2] = kd;
      scal[3] = 0.5f * (lo + hi);
    }
  }
  __syncthreads();

  // precompute exps once (lambda fixed): passes have no transcendentals
  const float lamL2 = scal[0];
  const float mid = scal[3];
  float EAx[TPT], EBx[TPT], EAy[TPT], EBy[TPT];
#pragma unroll
  for (int k = 0; k < TPT; ++k) {
    if (base + k < MSEL) {
      float X = lamL2 * (xr[k] - mid);
      EAx[k] = fexp2(X);
      EBx[k] = fexp2(-X);
      float Y = lamL2 * (yr[k] - mid);
      EAy[k] = fexp2(Y);
      EBy[k] = fexp2(-Y);
    } else {
      EAx[k] = EBx[k] = EAy[k] = EBy[k] = 0.f;
    }
  }

  // Sinkhorn chain; scal slots: 4=Sx, 5=Sy, 6=lX, 7=lY
  float zx[TPT], zy[TPT];
#pragma unroll
  for (int k = 0; k < TPT; ++k) { zx[k] = 0.f; zy[k] = 0.f; }
  do_pass<0>(lds, zx, zx, EAy, EBy, EAx, EBx, px, 0, 0, 0, 0);
  do_pass<1>(lds, zx, zy, EAx, EBx, EAy, EBy, py, 5, 7, 4, 6);
  do_pass<2>(lds, zy, zx, EAy, EBy, EAx, EBx, px, 4, 6, 5, 7);
  for (int it = 1; it < 10; ++it) {
    do_pass<2>(lds, zx, zy, EAx, EBx, EAy, EBy, py, 5, 7, 4, 6);
    do_pass<2>(lds, zy, zx, EAy, EBy, EAx, EBx, px, 4, 6, 5, 7);
  }

  // D-pass
  float* PrefA = lds + LPREF;
  float* SufB  = lds + LSUFB;
  const float delta = scal[1], kd2 = scal[2];
  const float Sx = scal[4], Sy = scal[5], lX = scal[6], lY = scal[7];
  const float cin_v = 1e-6f * Sy + lY * kd2;
  const float cin_u = 1e-6f * Sx + lX * kd2;

  float vv[TPT];
#pragma unroll
  for (int k = 0; k < TPT; ++k)
    vv[k] = (base + k < MSEL) ? au * frcp(zx[k] + cin_v) : 0.f;

  float dvk[TPT];
  float aa[TPT], bb[TPT];
  // sub1: a=v*2^X, b=v*2^-X  ->  y*(e^-Y*P1 - e^+Y*S1)
#pragma unroll
  for (int k = 0; k < TPT; ++k) { aa[k] = vv[k] * EAx[k]; bb[k] = vv[k] * EBx[k]; }
  scan_ab<false>(aa, bb, 0.f, lds, 0, 0, 0.f);
#pragma unroll
  for (int k = 0; k < TPT; ++k) {
    int p = py[k];
    dvk[k] = yr[k] * (EBy[k] * PrefA[p] - EAy[k] * SufB[p]);
  }
  // sub2: a=v*x*2^X, b=v*x*2^-X  ->  -e^-Y*P2 + e^+Y*S2
#pragma unroll
  for (int k = 0; k < TPT; ++k) { aa[k] = vv[k] * xr[k] * EAx[k]; bb[k] = vv[k] * xr[k] * EBx[k]; }
  scan_ab<false>(aa, bb, 0.f, lds, 0, 0, 0.f);
#pragma unroll
  for (int k = 0; k < TPT; ++k) {
    int p = py[k];
    dvk[k] += -EBy[k] * PrefA[p] + EAy[k] * SufB[p];
  }
  // sub3: a=v, b=v*x  ->  1e-6*( y*(2*P5 - Sv) + 2*S6 - TVX ); Sv=red[48], TVX=SufB[0]
#pragma unroll
  for (int k = 0; k < TPT; ++k) { aa[k] = vv[k]; bb[k] = vv[k] * xr[k]; }
  scan_ab<false>(aa, bb, 0.f, lds, 0, 0, 0.f);
  const float Sv = red[48];
  const float TVX = SufB[0];
  float acc = 0.f;
#pragma unroll
  for (int k = 0; k < TPT; ++k) {
    if (base + k < MSEL) {
      int p = py[k];
      float d6 = dvk[k] + 1e-6f * (yr[k] * (2.f * PrefA[p] - Sv) + 2.f * SufB[p] - TVX);
      float u = au * frcp(zy[k] + cin_u);
      acc += u * d6;
    }
  }
  float Dc = block_reduce(acc, red);
  if (tid == 0) {
    float v_last = 0.5f / (kd2 * Sy + lY * (1.0f + 1e-6f));
    float D = Dc + delta * kd2 * (lY * Sv + v_last * Sy);
    out[0] = 2.0f * D;
    out[1] = 0.f;
    out[2] = 0.f;
    out[3] = 0.f;
  }
}

extern "C" void kernel_launch(void* const* d_in, const int* in_sizes, int n_in,
                              void* d_out, int out_size, void* d_ws, size_t ws_size,
                              hipStream_t stream) {
  const float* yp = (const float*)d_in[0];
  float* wsF = (float*)d_ws;
  int* wsI = (int*)d_ws;
  float* out = (float*)d_out;

  hipMemsetAsync(d_ws, 0, ZERO_BYTES, stream);
  k_hist<<<79, 512, 0, stream>>>(yp, wsI);
  k_cand<<<dim3(40, 2), 512, 0, stream>>>(yp, wsI, wsF);
  k_rankc<<<dim3(16, 16, 2), 512, 0, stream>>>(wsI, wsF, wsI);
  k_solve<<<1, NTH, SOLVE_LDS_BYTES, stream>>>(wsF, wsI, out);
}